// Round 5
// baseline (219.644 us; speedup 1.0000x reference)
//
#include <hip/hip_runtime.h>
#include <hip/hip_bf16.h>

// GAT layer: N=4096, F_IN=128, F_OUT=64, HEADS=4.
// R16: remove the barrier lockstep entirely. R12-R15 all sat at 42-48us with
// MfmaUtil ~8% / VALUBusy ~40% / occ 34%: the per-chunk __syncthreads pair
// (a) convoys all 8 waves and (b) blocks compiler pipelining across chunks
// (R15 proved it: prefetch regs were demoted across the barrier, VGPR stayed
// 48). New gat_main: WAVE-INDEPENDENT. 1024 blocks x 512thr; block = (head,
// 16 rows); its 8 waves = 8-way column split (512 cols each, 16 MFMA steps).
// No LDS H staging -- B-fragments come straight from HbfT via L2 (512 KB
// per-head panel, XCD-affine h=id&3). Zero barriers in the loop -> compiler
// pipelines loads freely; waves free-run. One barrier at the end for the
// 8-way LDS partial reduction + fused normalize + store.
// Kernels: pack_bits -> gat_prep -> gat_main (fused) -> gat_fin (tiny).

#define NN 4096
#define FIN 128
#define FOUT 64
#define NH 4

typedef __attribute__((ext_vector_type(8))) short bf16x8;
typedef __attribute__((ext_vector_type(4))) float f32x4;
typedef __attribute__((ext_vector_type(4))) unsigned int u32x4;

__device__ __forceinline__ unsigned short f32_bf16(float f) {
    unsigned u = __builtin_bit_cast(unsigned, f);
    u += 0x7fffu + ((u >> 16) & 1u);          // round-to-nearest-even
    return (unsigned short)(u >> 16);
}

// ---------------- Kernel 0: pack A (int32 0/1) into bitmask ----------------
__global__ __launch_bounds__(256) void pack_bits(
    const int* __restrict__ A, unsigned long long* __restrict__ Abits)
{
    const int row  = blockIdx.x;
    const int lane = threadIdx.x & 63;
    const int wv   = threadIdx.x >> 6;
    const int* arow = A + (size_t)row * NN;
    #pragma unroll 4
    for (int c = 0; c < 16; ++c) {
        const int col = c * 256 + wv * 64 + lane;
        unsigned long long m = __ballot(__builtin_nontemporal_load(&arow[col]) > 0);
        if (lane == 0) Abits[(size_t)row * 64 + c * 4 + wv] = m;
    }
}

// ---------------- Kernel 1: prep ----------------
__global__ __launch_bounds__(256) void gat_prep(
    const float* __restrict__ X, const float* __restrict__ W,
    const float* __restrict__ b, const float* __restrict__ att,
    unsigned short* __restrict__ HbfT, float* __restrict__ Hrow,
    float* __restrict__ s_out, float* __restrict__ d_out,
    float* __restrict__ es_g, float* __restrict__ es2_g,
    float* __restrict__ ed_g, float* __restrict__ ed2_g)
{
    const int rb = blockIdx.x;           // 0..127
    const int h  = blockIdx.y;           // 0..3
    const int n0 = rb * 32;
    const int t  = threadIdx.x;          // 0..255

    __shared__ float Xl[32][132];
    __shared__ float Wt[128][68];

    for (int g = t; g < 32 * 32; g += 256) {
        int row = g >> 5, c4 = g & 31;
        float4 v = *(const float4*)&X[(size_t)(n0 + row) * FIN + c4 * 4];
        *(float4*)&Xl[row][c4 * 4] = v;
    }
    for (int g = t; g < 64 * 32; g += 256) {
        int o = g >> 5, c4 = g & 31;
        float4 v = *(const float4*)&W[((size_t)h * FOUT + o) * FIN + c4 * 4];
        Wt[c4 * 4 + 0][o] = v.x; Wt[c4 * 4 + 1][o] = v.y;
        Wt[c4 * 4 + 2][o] = v.z; Wt[c4 * 4 + 3][o] = v.w;
    }
    __syncthreads();

    const int rg = t >> 4;               // rows rg*2 .. rg*2+1
    const int og = t & 15;               // cols og*4 .. og*4+3
    float acc[2][4] = {};

    #pragma unroll 4
    for (int f4 = 0; f4 < 32; ++f4) {
        float xv[2][4], wv[4][4];
        #pragma unroll
        for (int i = 0; i < 2; ++i) {
            float4 tmp = *(const float4*)&Xl[rg * 2 + i][f4 * 4];
            xv[i][0] = tmp.x; xv[i][1] = tmp.y; xv[i][2] = tmp.z; xv[i][3] = tmp.w;
        }
        #pragma unroll
        for (int k = 0; k < 4; ++k) {
            float4 tmp = *(const float4*)&Wt[f4 * 4 + k][og * 4];
            wv[k][0] = tmp.x; wv[k][1] = tmp.y; wv[k][2] = tmp.z; wv[k][3] = tmp.w;
        }
        #pragma unroll
        for (int i = 0; i < 2; ++i)
            #pragma unroll
            for (int k = 0; k < 4; ++k)
                #pragma unroll
                for (int jj = 0; jj < 4; ++jj)
                    acc[i][jj] = fmaf(xv[i][k], wv[k][jj], acc[i][jj]);
    }

    float bb[4], as_[4], ad_[4];
    #pragma unroll
    for (int jj = 0; jj < 4; ++jj) {
        bb[jj]  = b[h * FOUT + og * 4 + jj];
        as_[jj] = att[h * 2 * FOUT + og * 4 + jj];
        ad_[jj] = att[h * 2 * FOUT + FOUT + og * 4 + jj];
    }
    #pragma unroll
    for (int i = 0; i < 2; ++i)
        #pragma unroll
        for (int jj = 0; jj < 4; ++jj)
            acc[i][jj] += bb[jj];

    float sp[2] = {0.f, 0.f}, dp[2] = {0.f, 0.f};
    #pragma unroll
    for (int i = 0; i < 2; ++i)
        #pragma unroll
        for (int jj = 0; jj < 4; ++jj) {
            sp[i] = fmaf(acc[i][jj], as_[jj], sp[i]);
            dp[i] = fmaf(acc[i][jj], ad_[jj], dp[i]);
        }
    #pragma unroll
    for (int off = 1; off < 16; off <<= 1) {
        #pragma unroll
        for (int i = 0; i < 2; ++i) {
            sp[i] += __shfl_xor(sp[i], off);
            dp[i] += __shfl_xor(dp[i], off);
        }
    }
    if (og == 0) {
        #pragma unroll
        for (int i = 0; i < 2; ++i) {
            int nn = n0 + rg * 2 + i;
            s_out[h * NN + nn]  = sp[i];
            d_out[h * NN + nn]  = dp[i];
            es_g [h * NN + nn]  = __expf(sp[i]);
            es2_g[h * NN + nn]  = __expf(0.01f * sp[i]);
            ed_g [h * NN + nn]  = __expf(dp[i]);
            ed2_g[h * NN + nn]  = __expf(0.01f * dp[i]);
        }
    }

    #pragma unroll
    for (int i = 0; i < 2; ++i) {
        float4 v = make_float4(acc[i][0], acc[i][1], acc[i][2], acc[i][3]);
        *(float4*)&Hrow[((size_t)h * NN + n0 + rg * 2 + i) * FOUT + og * 4] = v;
    }
    #pragma unroll
    for (int jj = 0; jj < 4; ++jj) {
        int o = og * 4 + jj;
        ushort2 p;
        p.x = f32_bf16(acc[0][jj]);
        p.y = f32_bf16(acc[1][jj]);
        *(ushort2*)&HbfT[((size_t)h * FOUT + o) * NN + n0 + rg * 2] = p;
    }
}

// ---------------- Kernel 2: fused masked softmax-aggregate ------------------
// Grid 1024 x 512thr. id -> h = id&3 (XCD-affine), rgp = id>>2 (16 rows).
// 8 waves = 8-way column split of the same 16 rows; wave w owns cols
// [w*512, w*512+512) = 16 MFMA steps of 32 cols. NO LDS staging, NO barriers
// in the loop: B-fragments load directly from HbfT (L2-resident). Epilogue:
// one barrier, 8-way partial reduction in LDS, fused normalize + store.
__global__ __launch_bounds__(512, 4) void gat_main(
    const unsigned* __restrict__ Abits, const unsigned short* __restrict__ HbfT,
    const float* __restrict__ s_g, const float* __restrict__ d_g,
    const float* __restrict__ es_g, const float* __restrict__ es2_g,
    const float* __restrict__ ed_g, const float* __restrict__ ed2_g,
    const float* __restrict__ Hrow, float* __restrict__ outH)
{
    const int id   = blockIdx.x;         // 0..1023
    const int h    = id & 3;
    const int rgp  = id >> 2;            // 0..255
    const int n0   = rgp * 16;
    const int tid  = threadIdx.x;        // 0..511
    const int w    = tid >> 6;           // wave 0..7 = column split
    const int lane = tid & 63;
    const int r    = lane & 15;          // A row within group / C col
    const int q    = lane >> 4;          // quad
    const int qs   = q * 8;
    const int wc0  = w * 512;            // this wave's column base

    __shared__ float red[7][16][68];     // 29.8 KB epilogue-only
    __shared__ float redl[7][16];

    const int nrow = n0 + r;
    const float es  = es_g [h * NN + nrow];
    const float es2 = es2_g[h * NN + nrow];

    const unsigned* bitsPtr = Abits + (size_t)nrow * 128 + (wc0 >> 5);
    const float* edh  = ed_g  + h * NN + wc0 + qs;
    const float* ed2h = ed2_g + h * NN + wc0 + qs;
    // B fragment base: lane (q,r) reads H^T[o = r + 16k][c = wc0 + step*32 + q*8 ..+8]
    const unsigned short* srcH =
        HbfT + ((size_t)(h * FOUT + r) * NN) + wc0 + q * 8;

    bf16x8 ones;
    #pragma unroll
    for (int i = 0; i < 8; ++i) ones[i] = (short)0x3F80;   // bf16 1.0

    f32x4 acc0 = {0,0,0,0}, acc1 = {0,0,0,0}, acc2 = {0,0,0,0},
          acc3 = {0,0,0,0}, accl = {0,0,0,0};

    #pragma unroll 2
    for (int t = 0; t < 16; ++t) {
        const int cb = t * 32;
        // all loads issued up front; no barriers -> compiler pipelines freely
        const unsigned bitsW = bitsPtr[t];
        const float4 e0 = *(const float4*)&edh [cb];
        const float4 e1 = *(const float4*)&edh [cb + 4];
        const float4 g0 = *(const float4*)&ed2h[cb];
        const float4 g1 = *(const float4*)&ed2h[cb + 4];
        const bf16x8 b0 = *(const bf16x8*)&srcH[cb];
        const bf16x8 b1 = *(const bf16x8*)&srcH[16 * NN + cb];
        const bf16x8 b2 = *(const bf16x8*)&srcH[32 * NN + cb];
        const bf16x8 b3 = *(const bf16x8*)&srcH[48 * NN + cb];

        const unsigned bits8 = bitsW >> qs;
        const float edv [8] = {e0.x, e0.y, e0.z, e0.w, e1.x, e1.y, e1.z, e1.w};
        const float ed2v[8] = {g0.x, g0.y, g0.z, g0.w, g1.x, g1.y, g1.z, g1.w};

        u32x4 afu;
        #pragma unroll
        for (int p = 0; p < 4; ++p) {
            const int j0 = 2 * p, j1 = 2 * p + 1;
            float wa = (bits8 & (1u << j0))
                     ? fmaxf(es * edv[j0], es2 * ed2v[j0]) : 0.0f;
            float wb = (bits8 & (1u << j1))
                     ? fmaxf(es * edv[j1], es2 * ed2v[j1]) : 0.0f;
            __hip_bfloat162 pk = __float22bfloat162_rn(make_float2(wa, wb));
            unsigned u;
            __builtin_memcpy(&u, &pk, sizeof(u));   // v_cvt_pk path
            afu[p] = u;
        }
        const bf16x8 af = __builtin_bit_cast(bf16x8, afu);

        acc0 = __builtin_amdgcn_mfma_f32_16x16x32_bf16(af, b0,   acc0, 0, 0, 0);
        acc1 = __builtin_amdgcn_mfma_f32_16x16x32_bf16(af, b1,   acc1, 0, 0, 0);
        acc2 = __builtin_amdgcn_mfma_f32_16x16x32_bf16(af, b2,   acc2, 0, 0, 0);
        acc3 = __builtin_amdgcn_mfma_f32_16x16x32_bf16(af, b3,   acc3, 0, 0, 0);
        accl = __builtin_amdgcn_mfma_f32_16x16x32_bf16(af, ones, accl, 0, 0, 0);
    }

    // ---- 8-way column-split reduction: waves 1..7 dump, wave 0 reduces ----
    if (w > 0) {
        #pragma unroll
        for (int reg = 0; reg < 4; ++reg) {
            const int rr = q * 4 + reg;
            red[w - 1][rr][ 0 + r] = acc0[reg];
            red[w - 1][rr][16 + r] = acc1[reg];
            red[w - 1][rr][32 + r] = acc2[reg];
            red[w - 1][rr][48 + r] = acc3[reg];
        }
        if (r == 0) {
            #pragma unroll
            for (int reg = 0; reg < 4; ++reg)
                redl[w - 1][q * 4 + reg] = accl[reg];
        }
    }
    __syncthreads();
    if (w == 0) {
        #pragma unroll
        for (int kk = 0; kk < 7; ++kk) {
            #pragma unroll
            for (int reg = 0; reg < 4; ++reg) {
                const int rr = q * 4 + reg;
                acc0[reg] += red[kk][rr][ 0 + r];
                acc1[reg] += red[kk][rr][16 + r];
                acc2[reg] += red[kk][rr][32 + r];
                acc3[reg] += red[kk][rr][48 + r];
                accl[reg] += redl[kk][rr];
            }
        }
        // ---- fused normalize + diagonal + store per-head output ----
        #pragma unroll
        for (int reg = 0; reg < 4; ++reg) {
            const int rr  = q * 4 + reg;
            const int nn2 = n0 + rr;
            const float tt = s_g[h * NN + nn2] + d_g[h * NN + nn2];
            const float wd = __expf(fmaxf(tt, 0.01f * tt));
            const float inv = 0.25f / (accl[reg] + wd);
            const float* hr = &Hrow[((size_t)h * NN + nn2) * FOUT];
            float*       ob = &outH[((size_t)h * NN + nn2) * FOUT];
            ob[ 0 + r] = (acc0[reg] + wd * hr[ 0 + r]) * inv;
            ob[16 + r] = (acc1[reg] + wd * hr[16 + r]) * inv;
            ob[32 + r] = (acc2[reg] + wd * hr[32 + r]) * inv;
            ob[48 + r] = (acc3[reg] + wd * hr[48 + r]) * inv;
        }
    }
}

// ---------------- Kernel 3: tiny finalize — sum 4 heads ----------------
__global__ __launch_bounds__(256) void gat_fin(
    const float* __restrict__ outH, float* __restrict__ out)
{
    const int i = blockIdx.x * 256 + threadIdx.x;    // 0..65535 float4s
    const f32x4* p = (const f32x4*)outH;
    f32x4 v0 = __builtin_nontemporal_load(p + i);
    f32x4 v1 = __builtin_nontemporal_load(p + i +  65536);
    f32x4 v2 = __builtin_nontemporal_load(p + i + 131072);
    f32x4 v3 = __builtin_nontemporal_load(p + i + 196608);
    f32x4 s = (v0 + v1) + (v2 + v3);
    *((f32x4*)out + i) = s;
}

extern "C" void kernel_launch(void* const* d_in, const int* in_sizes, int n_in,
                              void* d_out, int out_size, void* d_ws, size_t ws_size,
                              hipStream_t stream) {
    const float* X   = (const float*)d_in[0];
    const int*   A   = (const int*)  d_in[1];
    const float* W   = (const float*)d_in[2];
    const float* b   = (const float*)d_in[3];
    const float* att = (const float*)d_in[4];
    float* out = (float*)d_out;

    char* ws = (char*)d_ws;
    unsigned short* HbfT = (unsigned short*)ws;                    // 2 MB
    size_t off = (size_t)NH * FOUT * NN * 2;
    float* s_buf   = (float*)(ws + off);  off += (size_t)NH * NN * 4;
    float* d_buf   = (float*)(ws + off);  off += (size_t)NH * NN * 4;
    float* es_buf  = (float*)(ws + off);  off += (size_t)NH * NN * 4;
    float* es2_buf = (float*)(ws + off);  off += (size_t)NH * NN * 4;
    float* ed_buf  = (float*)(ws + off);  off += (size_t)NH * NN * 4;
    float* ed2_buf = (float*)(ws + off);  off += (size_t)NH * NN * 4;
    unsigned long long* Abits = (unsigned long long*)(ws + off);
    off += (size_t)NN * 64 * 8;                                         // 2 MB
    float* Hrow   = (float*)(ws + off);
    off += (size_t)NH * NN * FOUT * 4;                                  // 4 MB
    float* outH   = (float*)(ws + off);
    off += (size_t)NH * NN * FOUT * 4;                                  // 4 MB

    pack_bits<<<NN, 256, 0, stream>>>(A, Abits);
    gat_prep<<<dim3(128, 4), 256, 0, stream>>>(X, W, b, att, HbfT, Hrow,
                                               s_buf, d_buf,
                                               es_buf, es2_buf, ed_buf, ed2_buf);
    gat_main<<<1024, 512, 0, stream>>>((const unsigned*)Abits, HbfT,
                                       s_buf, d_buf,
                                       es_buf, es2_buf, ed_buf, ed2_buf,
                                       Hrow, outH);
    gat_fin<<<256, 256, 0, stream>>>(outH, out);
}

// Round 6
// 161.781 us; speedup vs baseline: 1.3577x; 1.3577x over previous
//
#include <hip/hip_runtime.h>
#include <hip/hip_bf16.h>

// GAT layer: N=4096, F_IN=128, F_OUT=64, HEADS=4.
// R17: back to the R14 staged-barrier skeleton (R16's direct-L2 fragments
// regressed 2x from L2 request amplification). Two deltas vs R14:
// (a) ed/ed2 + adjacency bits are now LDS-staged one chunk ahead (load->reg
//     ->ds_write BEFORE the barrier -- the only prefetch form the compiler
//     keeps, per R15's demotion lesson). After the barrier the whole compute
//     reads only LDS/registers; no L2 latency on the critical path.
//     bits buffer stride 9 (conflict-free; R12's stride-5 had 65K conflicts).
// (b) 256-col chunks (16 barriers instead of 32): halves barrier drains,
//     doubles independent per-chunk work. LDS 72KB/block, 2 blocks/CU.
// Kernels: pack_bits -> gat_prep -> gat_main (fused) -> gat_fin (tiny).

#define NN 4096
#define FIN 128
#define FOUT 64
#define NH 4

typedef __attribute__((ext_vector_type(8))) short bf16x8;
typedef __attribute__((ext_vector_type(4))) float f32x4;
typedef __attribute__((ext_vector_type(4))) unsigned int u32x4;

__device__ __forceinline__ unsigned short f32_bf16(float f) {
    unsigned u = __builtin_bit_cast(unsigned, f);
    u += 0x7fffu + ((u >> 16) & 1u);          // round-to-nearest-even
    return (unsigned short)(u >> 16);
}

// ---------------- Kernel 0: pack A (int32 0/1) into bitmask ----------------
__global__ __launch_bounds__(256) void pack_bits(
    const int* __restrict__ A, unsigned long long* __restrict__ Abits)
{
    const int row  = blockIdx.x;
    const int lane = threadIdx.x & 63;
    const int wv   = threadIdx.x >> 6;
    const int* arow = A + (size_t)row * NN;
    #pragma unroll 4
    for (int c = 0; c < 16; ++c) {
        const int col = c * 256 + wv * 64 + lane;
        unsigned long long m = __ballot(__builtin_nontemporal_load(&arow[col]) > 0);
        if (lane == 0) Abits[(size_t)row * 64 + c * 4 + wv] = m;
    }
}

// ---------------- Kernel 1: prep ----------------
__global__ __launch_bounds__(256) void gat_prep(
    const float* __restrict__ X, const float* __restrict__ W,
    const float* __restrict__ b, const float* __restrict__ att,
    unsigned short* __restrict__ HbfT, float* __restrict__ Hrow,
    float* __restrict__ s_out, float* __restrict__ d_out,
    float* __restrict__ es_g, float* __restrict__ es2_g,
    float* __restrict__ ed_g, float* __restrict__ ed2_g)
{
    const int rb = blockIdx.x;           // 0..127
    const int h  = blockIdx.y;           // 0..3
    const int n0 = rb * 32;
    const int t  = threadIdx.x;          // 0..255

    __shared__ float Xl[32][132];
    __shared__ float Wt[128][68];

    for (int g = t; g < 32 * 32; g += 256) {
        int row = g >> 5, c4 = g & 31;
        float4 v = *(const float4*)&X[(size_t)(n0 + row) * FIN + c4 * 4];
        *(float4*)&Xl[row][c4 * 4] = v;
    }
    for (int g = t; g < 64 * 32; g += 256) {
        int o = g >> 5, c4 = g & 31;
        float4 v = *(const float4*)&W[((size_t)h * FOUT + o) * FIN + c4 * 4];
        Wt[c4 * 4 + 0][o] = v.x; Wt[c4 * 4 + 1][o] = v.y;
        Wt[c4 * 4 + 2][o] = v.z; Wt[c4 * 4 + 3][o] = v.w;
    }
    __syncthreads();

    const int rg = t >> 4;               // rows rg*2 .. rg*2+1
    const int og = t & 15;               // cols og*4 .. og*4+3
    float acc[2][4] = {};

    #pragma unroll 4
    for (int f4 = 0; f4 < 32; ++f4) {
        float xv[2][4], wv[4][4];
        #pragma unroll
        for (int i = 0; i < 2; ++i) {
            float4 tmp = *(const float4*)&Xl[rg * 2 + i][f4 * 4];
            xv[i][0] = tmp.x; xv[i][1] = tmp.y; xv[i][2] = tmp.z; xv[i][3] = tmp.w;
        }
        #pragma unroll
        for (int k = 0; k < 4; ++k) {
            float4 tmp = *(const float4*)&Wt[f4 * 4 + k][og * 4];
            wv[k][0] = tmp.x; wv[k][1] = tmp.y; wv[k][2] = tmp.z; wv[k][3] = tmp.w;
        }
        #pragma unroll
        for (int i = 0; i < 2; ++i)
            #pragma unroll
            for (int k = 0; k < 4; ++k)
                #pragma unroll
                for (int jj = 0; jj < 4; ++jj)
                    acc[i][jj] = fmaf(xv[i][k], wv[k][jj], acc[i][jj]);
    }

    float bb[4], as_[4], ad_[4];
    #pragma unroll
    for (int jj = 0; jj < 4; ++jj) {
        bb[jj]  = b[h * FOUT + og * 4 + jj];
        as_[jj] = att[h * 2 * FOUT + og * 4 + jj];
        ad_[jj] = att[h * 2 * FOUT + FOUT + og * 4 + jj];
    }
    #pragma unroll
    for (int i = 0; i < 2; ++i)
        #pragma unroll
        for (int jj = 0; jj < 4; ++jj)
            acc[i][jj] += bb[jj];

    float sp[2] = {0.f, 0.f}, dp[2] = {0.f, 0.f};
    #pragma unroll
    for (int i = 0; i < 2; ++i)
        #pragma unroll
        for (int jj = 0; jj < 4; ++jj) {
            sp[i] = fmaf(acc[i][jj], as_[jj], sp[i]);
            dp[i] = fmaf(acc[i][jj], ad_[jj], dp[i]);
        }
    #pragma unroll
    for (int off = 1; off < 16; off <<= 1) {
        #pragma unroll
        for (int i = 0; i < 2; ++i) {
            sp[i] += __shfl_xor(sp[i], off);
            dp[i] += __shfl_xor(dp[i], off);
        }
    }
    if (og == 0) {
        #pragma unroll
        for (int i = 0; i < 2; ++i) {
            int nn = n0 + rg * 2 + i;
            s_out[h * NN + nn]  = sp[i];
            d_out[h * NN + nn]  = dp[i];
            es_g [h * NN + nn]  = __expf(sp[i]);
            es2_g[h * NN + nn]  = __expf(0.01f * sp[i]);
            ed_g [h * NN + nn]  = __expf(dp[i]);
            ed2_g[h * NN + nn]  = __expf(0.01f * dp[i]);
        }
    }

    #pragma unroll
    for (int i = 0; i < 2; ++i) {
        float4 v = make_float4(acc[i][0], acc[i][1], acc[i][2], acc[i][3]);
        *(float4*)&Hrow[((size_t)h * NN + n0 + rg * 2 + i) * FOUT + og * 4] = v;
    }
    #pragma unroll
    for (int jj = 0; jj < 4; ++jj) {
        int o = og * 4 + jj;
        ushort2 p;
        p.x = f32_bf16(acc[0][jj]);
        p.y = f32_bf16(acc[1][jj]);
        *(ushort2*)&HbfT[((size_t)h * FOUT + o) * NN + n0 + rg * 2] = p;
    }
}

// ---------------- Kernel 2: fused masked softmax-aggregate ------------------
// Grid 512 x 512thr. id -> h = id&3, tile = id>>2 (32 rows). 8 waves:
// rg = w&1 (16 rows), kg = w>>1; wave kg handles 32-col groups {kg, kg+4} of
// each 256-col chunk (16 chunks). All chunk inputs (H panel, ed/ed2, bits)
// double-buffered in LDS, staged one chunk ahead via load->reg->ds_write
// before the barrier. Epilogue: LDS K-reduction (aliases H), fused
// normalize + diagonal + store.
struct SMem {
    union {
        __align__(16) unsigned short H[2][64][256];  // 64 KB dbuf
        struct {
            float red[6][16][68];                    // 25.5 KB (pad 68)
            float redl[6][16];
        } fin;
    };
    unsigned bits[2][32][9];                         // 2.25 KB (stride 9: conflict-free)
    float ed [2][256];                               // 2 KB
    float ed2[2][256];                               // 2 KB
};

__global__ __launch_bounds__(512, 4) void gat_main(
    const unsigned* __restrict__ Abits, const unsigned short* __restrict__ HbfT,
    const float* __restrict__ s_g, const float* __restrict__ d_g,
    const float* __restrict__ es_g, const float* __restrict__ es2_g,
    const float* __restrict__ ed_g, const float* __restrict__ ed2_g,
    const float* __restrict__ Hrow, float* __restrict__ outH)
{
    const int id   = blockIdx.x;         // 0..511
    const int h    = id & 3;
    const int tile = id >> 2;            // 0..127
    const int n0   = tile * 32;
    const int tid  = threadIdx.x;        // 0..511
    const int w    = tid >> 6;           // wave 0..7
    const int lane = tid & 63;
    const int r    = lane & 15;          // A row within 16-row group / C col
    const int q    = lane >> 4;          // quad
    const int qs   = q * 8;
    const int rg   = w & 1;              // row group
    const int kg   = w >> 1;             // col-group pair {kg, kg+4}

    __shared__ SMem sm;                  // ~72 KB -> 2 blocks/CU

    const int nrow = n0 + rg * 16 + r;
    const float es  = es_g [h * NN + nrow];
    const float es2 = es2_g[h * NN + nrow];

    const int bb = ((kg * 4 + q) ^ r) & 15;   // swizzled 16B block (both groups)

    // ---- staging roles ----
    // H: all 512 threads stage 4x16B: rows {so, so+32}, c16 {sc, sc+16}
    const int so = tid >> 4;             // 0..31
    const int sc = tid & 15;
    const unsigned short* baseA = HbfT + ((size_t)(h * FOUT) + so)      * NN + sc * 8;
    const unsigned short* baseB = HbfT + ((size_t)(h * FOUT) + so + 32) * NN + sc * 8;
    const int offA0 = so * 256        + ((sc ^ so) & 15) * 8;
    const int offA1 = offA0 + 128;                           // c16+16 -> +128 ushorts
    const int offB0 = (so + 32) * 256 + ((sc ^ so) & 15) * 8;
    const int offB1 = offB0 + 128;
    // bits: threads 0..255 stage 32 rows x 8 words
    const int brow = tid >> 3, bwd = tid & 7;
    const unsigned* bitsSrc = Abits + (size_t)(n0 + brow) * 128 + bwd;
    // ed/ed2: threads 256..383 stage 2x256 floats (float4 each)
    const int ei = tid & 63;
    const float* edSrc  = ((tid < 320) ? ed_g : ed2_g) + (size_t)h * NN + ei * 4;
    float* edDst0 = (tid < 320) ? sm.ed[0] : sm.ed2[0];      // buffer 0 target
    float* edDst1 = (tid < 320) ? sm.ed[1] : sm.ed2[1];      // buffer 1 target

    bf16x8 ones;
    #pragma unroll
    for (int i = 0; i < 8; ++i) ones[i] = (short)0x3F80;   // bf16 1.0

    f32x4 acc0 = {0,0,0,0}, acc1 = {0,0,0,0}, acc2 = {0,0,0,0},
          acc3 = {0,0,0,0}, accl = {0,0,0,0};

    // ---- prologue: stage chunk 0 into buffer 0 ----
    {
        bf16x8 sA0 = *(const bf16x8*)&baseA[0];
        bf16x8 sA1 = *(const bf16x8*)&baseA[128];
        bf16x8 sB0 = *(const bf16x8*)&baseB[0];
        bf16x8 sB1 = *(const bf16x8*)&baseB[128];
        unsigned short* hw = &sm.H[0][0][0];
        *(bf16x8*)&hw[offA0] = sA0;
        *(bf16x8*)&hw[offA1] = sA1;
        *(bf16x8*)&hw[offB0] = sB0;
        *(bf16x8*)&hw[offB1] = sB1;
        if (tid < 256)      sm.bits[0][brow][bwd] = bitsSrc[0];
        else if (tid < 384) *(float4*)&edDst0[ei * 4] = *(const float4*)&edSrc[0];
    }
    __syncthreads();

    #pragma unroll 2
    for (int ch = 0; ch < 16; ++ch) {
        const int buf = ch & 1;
        const unsigned short* hb = buf ? &sm.H[1][0][0] : &sm.H[0][0][0];
        const unsigned (*bl)[9]  = buf ? sm.bits[1]     : sm.bits[0];
        const float* edl         = buf ? sm.ed[1]       : sm.ed[0];
        const float* ed2l        = buf ? sm.ed2[1]      : sm.ed2[0];

        // issue next chunk's global loads (consumed before the barrier)
        bf16x8 sA0, sA1, sB0, sB1; unsigned stBits = 0; float4 stEd;
        if (ch < 15) {
            const int c0n = (ch + 1) * 256;
            sA0 = *(const bf16x8*)&baseA[c0n];
            sA1 = *(const bf16x8*)&baseA[c0n + 128];
            sB0 = *(const bf16x8*)&baseB[c0n];
            sB1 = *(const bf16x8*)&baseB[c0n + 128];
            if (tid < 256)      stBits = bitsSrc[(ch + 1) * 8];
            else if (tid < 384) stEd = *(const float4*)&edSrc[c0n];
        }

        // ---- group a: cols [kg*32, +32) of this chunk ----
        {
            const unsigned bits8 = bl[rg * 16 + r][kg] >> qs;
            const float4 e0 = *(const float4*)&edl [kg * 32 + qs];
            const float4 e1 = *(const float4*)&edl [kg * 32 + qs + 4];
            const float4 g0 = *(const float4*)&ed2l[kg * 32 + qs];
            const float4 g1 = *(const float4*)&ed2l[kg * 32 + qs + 4];
            const float edv [8] = {e0.x, e0.y, e0.z, e0.w, e1.x, e1.y, e1.z, e1.w};
            const float ed2v[8] = {g0.x, g0.y, g0.z, g0.w, g1.x, g1.y, g1.z, g1.w};
            u32x4 afu;
            #pragma unroll
            for (int p = 0; p < 4; ++p) {
                const int j0 = 2 * p, j1 = 2 * p + 1;
                float wa = (bits8 & (1u << j0))
                         ? fmaxf(es * edv[j0], es2 * ed2v[j0]) : 0.0f;
                float wb = (bits8 & (1u << j1))
                         ? fmaxf(es * edv[j1], es2 * ed2v[j1]) : 0.0f;
                __hip_bfloat162 pk = __float22bfloat162_rn(make_float2(wa, wb));
                unsigned u;
                __builtin_memcpy(&u, &pk, sizeof(u));
                afu[p] = u;
            }
            const bf16x8 af = __builtin_bit_cast(bf16x8, afu);

            const bf16x8 b0 = *(const bf16x8*)&hb[(r     ) * 256 + bb * 8];
            const bf16x8 b1 = *(const bf16x8*)&hb[(r + 16) * 256 + bb * 8];
            const bf16x8 b2 = *(const bf16x8*)&hb[(r + 32) * 256 + bb * 8];
            const bf16x8 b3 = *(const bf16x8*)&hb[(r + 48) * 256 + bb * 8];

            acc0 = __builtin_amdgcn_mfma_f32_16x16x32_bf16(af, b0,   acc0, 0, 0, 0);
            acc1 = __builtin_amdgcn_mfma_f32_16x16x32_bf16(af, b1,   acc1, 0, 0, 0);
            acc2 = __builtin_amdgcn_mfma_f32_16x16x32_bf16(af, b2,   acc2, 0, 0, 0);
            acc3 = __builtin_amdgcn_mfma_f32_16x16x32_bf16(af, b3,   acc3, 0, 0, 0);
            accl = __builtin_amdgcn_mfma_f32_16x16x32_bf16(af, ones, accl, 0, 0, 0);
        }

        // ---- group b: cols [128 + kg*32, +32) of this chunk ----
        {
            const unsigned bits8 = bl[rg * 16 + r][kg + 4] >> qs;
            const float4 e0 = *(const float4*)&edl [128 + kg * 32 + qs];
            const float4 e1 = *(const float4*)&edl [128 + kg * 32 + qs + 4];
            const float4 g0 = *(const float4*)&ed2l[128 + kg * 32 + qs];
            const float4 g1 = *(const float4*)&ed2l[128 + kg * 32 + qs + 4];
            const float edv [8] = {e0.x, e0.y, e0.z, e0.w, e1.x, e1.y, e1.z, e1.w};
            const float ed2v[8] = {g0.x, g0.y, g0.z, g0.w, g1.x, g1.y, g1.z, g1.w};
            u32x4 afu;
            #pragma unroll
            for (int p = 0; p < 4; ++p) {
                const int j0 = 2 * p, j1 = 2 * p + 1;
                float wa = (bits8 & (1u << j0))
                         ? fmaxf(es * edv[j0], es2 * ed2v[j0]) : 0.0f;
                float wb = (bits8 & (1u << j1))
                         ? fmaxf(es * edv[j1], es2 * ed2v[j1]) : 0.0f;
                __hip_bfloat162 pk = __float22bfloat162_rn(make_float2(wa, wb));
                unsigned u;
                __builtin_memcpy(&u, &pk, sizeof(u));
                afu[p] = u;
            }
            const bf16x8 af = __builtin_bit_cast(bf16x8, afu);

            const bf16x8 b0 = *(const bf16x8*)&hb[(r     ) * 256 + 128 + bb * 8];
            const bf16x8 b1 = *(const bf16x8*)&hb[(r + 16) * 256 + 128 + bb * 8];
            const bf16x8 b2 = *(const bf16x8*)&hb[(r + 32) * 256 + 128 + bb * 8];
            const bf16x8 b3 = *(const bf16x8*)&hb[(r + 48) * 256 + 128 + bb * 8];

            acc0 = __builtin_amdgcn_mfma_f32_16x16x32_bf16(af, b0,   acc0, 0, 0, 0);
            acc1 = __builtin_amdgcn_mfma_f32_16x16x32_bf16(af, b1,   acc1, 0, 0, 0);
            acc2 = __builtin_amdgcn_mfma_f32_16x16x32_bf16(af, b2,   acc2, 0, 0, 0);
            acc3 = __builtin_amdgcn_mfma_f32_16x16x32_bf16(af, b3,   acc3, 0, 0, 0);
            accl = __builtin_amdgcn_mfma_f32_16x16x32_bf16(af, ones, accl, 0, 0, 0);
        }

        // ---- write staged regs to the other buffer (pre-barrier) ----
        if (ch < 15) {
            unsigned short* hw = buf ? &sm.H[0][0][0] : &sm.H[1][0][0];
            *(bf16x8*)&hw[offA0] = sA0;
            *(bf16x8*)&hw[offA1] = sA1;
            *(bf16x8*)&hw[offB0] = sB0;
            *(bf16x8*)&hw[offB1] = sB1;
            if (tid < 256) {
                unsigned* bw = buf ? &sm.bits[0][0][0] : &sm.bits[1][0][0];
                bw[brow * 9 + bwd] = stBits;
            } else if (tid < 384) {
                float* ew = buf ? edDst0 : edDst1;
                *(float4*)&ew[ei * 4] = stEd;
            }
        }
        __syncthreads();
    }

    // ---- K-partial reduction: kg 1..3 dump to LDS, kg 0 accumulates ----
    // (sm.fin aliases sm.H — all stage reads completed before last barrier)
    if (kg > 0) {
        const int widx = (kg - 1) * 2 + rg;
        #pragma unroll
        for (int reg = 0; reg < 4; ++reg) {
            const int rr = q * 4 + reg;
            sm.fin.red[widx][rr][ 0 + r] = acc0[reg];
            sm.fin.red[widx][rr][16 + r] = acc1[reg];
            sm.fin.red[widx][rr][32 + r] = acc2[reg];
            sm.fin.red[widx][rr][48 + r] = acc3[reg];
        }
        if (r == 0) {
            #pragma unroll
            for (int reg = 0; reg < 4; ++reg)
                sm.fin.redl[widx][q * 4 + reg] = accl[reg];
        }
    }
    __syncthreads();
    if (kg == 0) {
        #pragma unroll
        for (int kk = 0; kk < 3; ++kk) {
            const int widx = kk * 2 + rg;
            #pragma unroll
            for (int reg = 0; reg < 4; ++reg) {
                const int rr = q * 4 + reg;
                acc0[reg] += sm.fin.red[widx][rr][ 0 + r];
                acc1[reg] += sm.fin.red[widx][rr][16 + r];
                acc2[reg] += sm.fin.red[widx][rr][32 + r];
                acc3[reg] += sm.fin.red[widx][rr][48 + r];
                accl[reg] += sm.fin.redl[widx][rr];
            }
        }
        // ---- fused normalize + diagonal + store per-head output ----
        #pragma unroll
        for (int reg = 0; reg < 4; ++reg) {
            const int rr  = q * 4 + reg;
            const int nn2 = n0 + rg * 16 + rr;
            const float tt = s_g[h * NN + nn2] + d_g[h * NN + nn2];
            const float wd = __expf(fmaxf(tt, 0.01f * tt));
            const float inv = 0.25f / (accl[reg] + wd);
            const float* hr = &Hrow[((size_t)h * NN + nn2) * FOUT];
            float*       ob = &outH[((size_t)h * NN + nn2) * FOUT];
            ob[ 0 + r] = (acc0[reg] + wd * hr[ 0 + r]) * inv;
            ob[16 + r] = (acc1[reg] + wd * hr[16 + r]) * inv;
            ob[32 + r] = (acc2[reg] + wd * hr[32 + r]) * inv;
            ob[48 + r] = (acc3[reg] + wd * hr[48 + r]) * inv;
        }
    }
}

// ---------------- Kernel 3: tiny finalize — sum 4 heads ----------------
__global__ __launch_bounds__(256) void gat_fin(
    const float* __restrict__ outH, float* __restrict__ out)
{
    const int i = blockIdx.x * 256 + threadIdx.x;    // 0..65535 float4s
    const f32x4* p = (const f32x4*)outH;
    f32x4 v0 = __builtin_nontemporal_load(p + i);
    f32x4 v1 = __builtin_nontemporal_load(p + i +  65536);
    f32x4 v2 = __builtin_nontemporal_load(p + i + 131072);
    f32x4 v3 = __builtin_nontemporal_load(p + i + 196608);
    f32x4 s = (v0 + v1) + (v2 + v3);
    *((f32x4*)out + i) = s;
}

extern "C" void kernel_launch(void* const* d_in, const int* in_sizes, int n_in,
                              void* d_out, int out_size, void* d_ws, size_t ws_size,
                              hipStream_t stream) {
    const float* X   = (const float*)d_in[0];
    const int*   A   = (const int*)  d_in[1];
    const float* W   = (const float*)d_in[2];
    const float* b   = (const float*)d_in[3];
    const float* att = (const float*)d_in[4];
    float* out = (float*)d_out;

    char* ws = (char*)d_ws;
    unsigned short* HbfT = (unsigned short*)ws;                    // 2 MB
    size_t off = (size_t)NH * FOUT * NN * 2;
    float* s_buf   = (float*)(ws + off);  off += (size_t)NH * NN * 4;
    float* d_buf   = (float*)(ws + off);  off += (size_t)NH * NN * 4;
    float* es_buf  = (float*)(ws + off);  off += (size_t)NH * NN * 4;
    float* es2_buf = (float*)(ws + off);  off += (size_t)NH * NN * 4;
    float* ed_buf  = (float*)(ws + off);  off += (size_t)NH * NN * 4;
    float* ed2_buf = (float*)(ws + off);  off += (size_t)NH * NN * 4;
    unsigned long long* Abits = (unsigned long long*)(ws + off);
    off += (size_t)NN * 64 * 8;                                         // 2 MB
    float* Hrow   = (float*)(ws + off);
    off += (size_t)NH * NN * FOUT * 4;                                  // 4 MB
    float* outH   = (float*)(ws + off);
    off += (size_t)NH * NN * FOUT * 4;                                  // 4 MB

    pack_bits<<<NN, 256, 0, stream>>>(A, Abits);
    gat_prep<<<dim3(128, 4), 256, 0, stream>>>(X, W, b, att, HbfT, Hrow,
                                               s_buf, d_buf,
                                               es_buf, es2_buf, ed_buf, ed2_buf);
    gat_main<<<512, 512, 0, stream>>>((const unsigned*)Abits, HbfT,
                                      s_buf, d_buf,
                                      es_buf, es2_buf, ed_buf, ed2_buf,
                                      Hrow, outH);
    gat_fin<<<256, 256, 0, stream>>>(outH, out);
}